// Round 11
// baseline (218.986 us; speedup 1.0000x reference)
//
#include <hip/hip_runtime.h>
#include <hip/hip_bf16.h>

#define DIM   256
#define DH    64
#define NKS   64      // K_SLOTS
#define NH    4       // HEADS
#define SEQ   32768

typedef float f32x4  __attribute__((ext_vector_type(4)));
typedef short bf16x8 __attribute__((ext_vector_type(8)));

__device__ __forceinline__ unsigned short f2bf(float f) {
    union { __hip_bfloat16 b; unsigned short u; } v;
    v.b = __float2bfloat16(f);
    return v.u;
}
__device__ __forceinline__ unsigned int f2bf2(float lo, float hi) {
    return (unsigned int)f2bf(lo) | ((unsigned int)f2bf(hi) << 16);
}

// ---------------- K0: Q = LN(mu) @ Wq + bq  -> Q[64][256] fp32 ----------------
__global__ void k_q(const float* __restrict__ mu, const float* __restrict__ g,
                    const float* __restrict__ bb, const float* __restrict__ Wq,
                    const float* __restrict__ bq, float* __restrict__ Q) {
    __shared__ float nrm[DIM];
    __shared__ float red1[4], red2[4];
    const int k = blockIdx.x, t = threadIdx.x;
    float x = mu[k * DIM + t];
    float s = x;
    #pragma unroll
    for (int o = 1; o <= 32; o <<= 1) s += __shfl_xor(s, o);
    if ((t & 63) == 0) red1[t >> 6] = s;
    __syncthreads();
    const float mean = (red1[0] + red1[1] + red1[2] + red1[3]) * (1.0f / DIM);
    const float d = x - mean;
    float vs = d * d;
    #pragma unroll
    for (int o = 1; o <= 32; o <<= 1) vs += __shfl_xor(vs, o);
    if ((t & 63) == 0) red2[t >> 6] = vs;
    __syncthreads();
    const float var = (red2[0] + red2[1] + red2[2] + red2[3]) * (1.0f / DIM);
    nrm[t] = d * rsqrtf(var + 1e-5f) * g[t] + bb[t];
    __syncthreads();
    float acc = bq[t];
    for (int c = 0; c < DIM; ++c) acc += nrm[c] * Wq[c * DIM + t];
    Q[k * DIM + t] = acc;
}

// ---- K1: fold scores matrix + transpose. W2T[n][c] (bf16, c contiguous) ----
__global__ void k_fold(const float* __restrict__ Q, const float* __restrict__ Wk,
                       const float* __restrict__ bk, const float* __restrict__ Wv,
                       const float* __restrict__ bv,
                       unsigned short* __restrict__ W2T, float* __restrict__ b2) {
    const int n = blockIdx.x, t = threadIdx.x;
    __shared__ float q[DH];
    if (n < 256) {
        const int h = n >> 6, k = n & 63;
        if (t < DH) q[t] = Q[k * DIM + h * DH + t];
        __syncthreads();
        float acc = 0.f;
        #pragma unroll 8
        for (int d0 = 0; d0 < DH; ++d0) acc += Wk[t * DIM + h * DH + d0] * q[d0];
        W2T[n * 256 + t] = f2bf(acc * 0.125f);
        if (t == 0) {
            float ba = 0.f;
            for (int d0 = 0; d0 < DH; ++d0) ba += bk[h * DH + d0] * q[d0];
            b2[n] = ba * 0.125f;
        }
    } else {
        const int col = n - 256;
        W2T[n * 256 + t] = f2bf(Wv[t * DIM + col]);
        if (t == 0) b2[n] = bv[col];
    }
}

// ======== K2: k_fused — single pass, 8 waves, 2 blocks/CU ========
// Grid 512 = 4b x 128chunks (256 rows = 8 tiles of 32). 512 thr = 8 waves.
// Lesson stack: 16 waves => 1 block/CU convoy (r3-9); 8 waves @ <=128 regs
// => 2 blocks/CU works (r10 two-pass, 130us). This fuses the two passes back
// at 8 waves: X read ONCE, W/V stay in LDS (saves the 134MB W^T round trip
// + one 134MB X read vs r10). Both B-panels (32 score + 32 V cols per wave)
// are STREAMED from L2-resident W2T (262KB, shared by all 512 blocks) —
// no persistent panel regs, so everything fits the (512,4) 128-reg cap:
// pv 32 + acc_s 16 + acc_v 16 + pf 16 + stream ~24 + misc ~15 ~= 120.
// LDS 67584 (round-8 proven layout): Xbuf dbuf 2x16K @0, W_lds @32768
// ([4h][64k] rows x 64B, XOR swz), V_lds @49152 ([256d] x 64B), Ssc @65536.
// Wave wid: scores (h=wid>>1, sh=wid&1) cols wid*32..+32; V cols wid*32..+32
// (same head h = wid>>1 -> one sinv serves W-write AND V-scale); PV (hp=wid>>1,
// dh=wid&1) covering 64k x 32d.
__global__ __launch_bounds__(512, 4)
void k_fused(const float* __restrict__ X, const unsigned short* __restrict__ W2T,
             const float* __restrict__ b2, float* __restrict__ num_p,
             float* __restrict__ den_p) {
    extern __shared__ __align__(16) unsigned char smem[];
    const int AB = 32768, VB = 49152, SB = 65536;
    const int tid  = threadIdx.x;
    const int lane = tid & 63;
    const int wid  = tid >> 6;
    const int l15  = lane & 15;
    const int lhi  = lane >> 4;
    const int bid   = blockIdx.x;
    const int b     = bid >> 7;
    const int chunk = bid & 127;
    const float* Xg = X + ((size_t)(b * SEQ + chunk * 256)) * DIM;

    const int h  = wid >> 1;    // score/V/PV head
    const int sh = wid & 1;     // slot half (scores)
    const int dh = wid & 1;     // d half (PV)

    const unsigned short* Bs = W2T + (size_t)(wid * 32 + l15) * 256;        // score panel rows
    const unsigned short* Bv = W2T + (size_t)(256 + wid * 32 + l15) * 256;  // V panel rows

    float bias_s[2], bias_v[2];
    #pragma unroll
    for (int ni = 0; ni < 2; ++ni) {
        bias_s[ni] = b2[wid * 32 + ni * 16 + l15];
        bias_v[ni] = b2[256 + wid * 32 + ni * 16 + l15];
    }

    f32x4 pv[4][2];
    #pragma unroll
    for (int mi = 0; mi < 4; ++mi)
        #pragma unroll
        for (int ni = 0; ni < 2; ++ni) pv[mi][ni] = (f32x4){0.f, 0.f, 0.f, 0.f};
    float den_acc[2] = {0.f, 0.f};

    float4 pf[4];
    // ---- prologue: stage tile 0 (32 rows x 256 f32 -> bf16, XOR swz) ----
    #pragma unroll
    for (int j = 0; j < 4; ++j) {
        const int f = j * 512 + tid;
        pf[j] = *(const float4*)(Xg + (f >> 6) * DIM + (f & 63) * 4);
    }
    #pragma unroll
    for (int j = 0; j < 4; ++j) {
        const int f = j * 512 + tid;
        const int row = f >> 6, c4 = f & 63;
        const int byte = row * 512 + ((c4 * 8) ^ ((row & 7) << 4));
        *(uint2*)(smem + byte) = make_uint2(f2bf2(pf[j].x, pf[j].y), f2bf2(pf[j].z, pf[j].w));
    }
    __syncthreads();

    for (int t = 0; t < 8; ++t) {
        const int tb = t & 1;
        const unsigned char* xbuf = smem + tb * 16384;

        // ---- [A] prefetch next X tile ----
        if (t < 7) {
            const float* Xt = Xg + (size_t)(t + 1) * 32 * DIM;
            #pragma unroll
            for (int j = 0; j < 4; ++j) {
                const int f = j * 512 + tid;
                pf[j] = *(const float4*)(Xt + (f >> 6) * DIM + (f & 63) * 4);
            }
        }

        // ---- [B] fused score+V GEMM (both B-panels streamed from L2) ----
        f32x4 acc_s[2][2], acc_v[2][2];
        #pragma unroll
        for (int si = 0; si < 2; ++si)
            #pragma unroll
            for (int ni = 0; ni < 2; ++ni) {
                acc_s[si][ni] = (f32x4){bias_s[ni], bias_s[ni], bias_s[ni], bias_s[ni]};
                acc_v[si][ni] = (f32x4){bias_v[ni], bias_v[ni], bias_v[ni], bias_v[ni]};
            }
        #pragma unroll 4
        for (int ks = 0; ks < 8; ++ks) {
            bf16x8 afr[2];
            #pragma unroll
            for (int si = 0; si < 2; ++si) {
                const int row  = si * 16 + l15;
                const int byte = row * 512 + ((ks * 64 + lhi * 16) ^ ((row & 7) << 4));
                afr[si] = *(const bf16x8*)(xbuf + byte);
            }
            #pragma unroll
            for (int ni = 0; ni < 2; ++ni) {
                const bf16x8 bs = *(const bf16x8*)(Bs + (size_t)ni * 16 * 256 + ks * 32 + lhi * 8);
                const bf16x8 bv = *(const bf16x8*)(Bv + (size_t)ni * 16 * 256 + ks * 32 + lhi * 8);
                #pragma unroll
                for (int si = 0; si < 2; ++si) {
                    acc_s[si][ni] = __builtin_amdgcn_mfma_f32_16x16x32_bf16(
                        afr[si], bs, acc_s[si][ni], 0, 0, 0);
                    acc_v[si][ni] = __builtin_amdgcn_mfma_f32_16x16x32_bf16(
                        afr[si], bv, acc_v[si][ni], 0, 0, 0);
                }
            }
        }

        // ---- [C] exp (no max; scores ~N(0,0.1), proven r5-10) + slot partials ----
        #pragma unroll
        for (int si = 0; si < 2; ++si) {
            #pragma unroll
            for (int ni = 0; ni < 2; ++ni)
                #pragma unroll
                for (int r = 0; r < 4; ++r)
                    acc_s[si][ni][r] = __expf(acc_s[si][ni][r]);
            #pragma unroll
            for (int r = 0; r < 4; ++r) {
                float p = acc_s[si][0][r] + acc_s[si][1][r];
                p += __shfl_xor(p, 1);
                p += __shfl_xor(p, 2);
                p += __shfl_xor(p, 4);
                p += __shfl_xor(p, 8);
                if (l15 == 0)
                    *(float*)(smem + SB + (((tb * 4 + h) * 2 + sh) * 32
                                           + si * 16 + lhi * 4 + r) * 4) = p;
            }
        }

        // ---- [D] barrier ----
        __syncthreads();

        // ---- [E] sinv; den; write W_lds (raw exp) + V_lds (V*sinv) + next X ----
        #pragma unroll
        for (int si = 0; si < 2; ++si) {
            const int sbase = SB + ((tb * 4 + h) * 2) * 128 + (si * 16 + lhi * 4) * 4;
            const f32x4 s0 = *(const f32x4*)(smem + sbase);
            const f32x4 s1 = *(const f32x4*)(smem + sbase + 128);
            float sinv[4];
            #pragma unroll
            for (int r = 0; r < 4; ++r) sinv[r] = 1.0f / (s0[r] + s1[r]);
            #pragma unroll
            for (int ni = 0; ni < 2; ++ni) {
                den_acc[ni] += acc_s[si][ni][0] * sinv[0] + acc_s[si][ni][1] * sinv[1]
                             + acc_s[si][ni][2] * sinv[2] + acc_s[si][ni][3] * sinv[3];
                const int k = sh * 32 + ni * 16 + l15;
                const int byteW = AB + (h * 64 + k) * 64
                                + ((si * 32 + lhi * 8) ^ (((k >> 1) & 3) << 4));
                *(uint2*)(smem + byteW) = make_uint2(
                    f2bf2(acc_s[si][ni][0], acc_s[si][ni][1]),
                    f2bf2(acc_s[si][ni][2], acc_s[si][ni][3]));
                const int d = wid * 32 + ni * 16 + l15;
                const int byteV = VB + d * 64
                                + ((si * 32 + lhi * 8) ^ (((d >> 1) & 3) << 4));
                *(uint2*)(smem + byteV) = make_uint2(
                    f2bf2(acc_v[si][ni][0] * sinv[0], acc_v[si][ni][1] * sinv[1]),
                    f2bf2(acc_v[si][ni][2] * sinv[2], acc_v[si][ni][3] * sinv[3]));
            }
        }
        if (t < 7) {
            unsigned char* nbuf = smem + (tb ^ 1) * 16384;
            #pragma unroll
            for (int j = 0; j < 4; ++j) {
                const int f = j * 512 + tid;
                const int row = f >> 6, c4 = f & 63;
                const int byte = row * 512 + ((c4 * 8) ^ ((row & 7) << 4));
                *(uint2*)(nbuf + byte) = make_uint2(f2bf2(pf[j].x, pf[j].y),
                                                    f2bf2(pf[j].z, pf[j].w));
            }
        }

        // ---- [F] barrier ----
        __syncthreads();

        // ---- [G] PV: pv[64k x 32d of head h] += W_lds · V_lds (K=32) ----
        {
            bf16x8 afr[4];
            #pragma unroll
            for (int mi = 0; mi < 4; ++mi) {
                const int k = mi * 16 + l15;
                afr[mi] = *(const bf16x8*)(smem + AB + (h * 64 + k) * 64
                                           + ((lhi * 16) ^ (((k >> 1) & 3) << 4)));
            }
            bf16x8 vfr[2];
            #pragma unroll
            for (int ni = 0; ni < 2; ++ni) {
                const int d = h * 64 + dh * 32 + ni * 16 + l15;
                vfr[ni] = *(const bf16x8*)(smem + VB + d * 64
                                           + ((lhi * 16) ^ (((d >> 1) & 3) << 4)));
            }
            #pragma unroll
            for (int mi = 0; mi < 4; ++mi)
                #pragma unroll
                for (int ni = 0; ni < 2; ++ni)
                    pv[mi][ni] = __builtin_amdgcn_mfma_f32_16x16x32_bf16(
                        afr[mi], vfr[ni], pv[mi][ni], 0, 0, 0);
        }
    }

    // ---- epilogue: partial stores (no atomics) ----
    #pragma unroll
    for (int mi = 0; mi < 4; ++mi)
        #pragma unroll
        for (int ni = 0; ni < 2; ++ni)
            #pragma unroll
            for (int r = 0; r < 4; ++r) {
                const int k = mi * 16 + lhi * 4 + r;
                const int d = dh * 32 + ni * 16 + l15;
                num_p[(((size_t)bid * 4 + h) * 64 + k) * 64 + d] = pv[mi][ni][r];
            }
    #pragma unroll
    for (int ni = 0; ni < 2; ++ni) {
        float v = den_acc[ni];
        v += __shfl_xor(v, 16);
        v += __shfl_xor(v, 32);
        if (lhi == 0)
            den_p[(size_t)bid * 256 + wid * 32 + ni * 16 + l15] = v;
    }
}

// ---- K3: reduce 128 chunk-partials; S_hat = num/(den+eps); LN ----
__global__ void k_final2(const float* __restrict__ num_p, const float* __restrict__ den_p,
                         const float* __restrict__ ga, const float* __restrict__ gb,
                         float* __restrict__ out) {
    __shared__ float red1[4], red2[4];
    const int b = blockIdx.x >> 6, k = blockIdx.x & 63;
    const int t = threadIdx.x;
    const int h = t >> 6, dd = t & 63;
    float nsum = 0.f, dsum = 0.f;
    #pragma unroll 8
    for (int c = 0; c < 128; ++c) {
        const size_t bid = (size_t)(b * 128 + c);
        nsum += num_p[((bid * 4 + h) * 64 + k) * 64 + dd];
        dsum += den_p[bid * 256 + h * 64 + k];
    }
    const float val = nsum / (dsum + 1e-20f);
    float s = val;
    #pragma unroll
    for (int o = 1; o <= 32; o <<= 1) s += __shfl_xor(s, o);
    if ((t & 63) == 0) red1[t >> 6] = s;
    __syncthreads();
    const float mean = (red1[0] + red1[1] + red1[2] + red1[3]) * (1.0f / DIM);
    const float d = val - mean;
    float vs = d * d;
    #pragma unroll
    for (int o = 1; o <= 32; o <<= 1) vs += __shfl_xor(vs, o);
    if ((t & 63) == 0) red2[t >> 6] = vs;
    __syncthreads();
    const float var = (red2[0] + red2[1] + red2[2] + red2[3]) * (1.0f / DIM);
    out[(size_t)(b * NKS + k) * DIM + t] = d * rsqrtf(var + 1e-5f) * ga[t] + gb[t];
}

extern "C" void kernel_launch(void* const* d_in, const int* in_sizes, int n_in,
                              void* d_out, int out_size, void* d_ws, size_t ws_size,
                              hipStream_t stream) {
    const float* X      = (const float*)d_in[0];
    const float* mu     = (const float*)d_in[1];
    const float* ln_s_g = (const float*)d_in[2];
    const float* ln_s_b = (const float*)d_in[3];
    const float* Wq     = (const float*)d_in[4];
    const float* bq     = (const float*)d_in[5];
    const float* Wk     = (const float*)d_in[6];
    const float* bk     = (const float*)d_in[7];
    const float* Wv     = (const float*)d_in[8];
    const float* bv     = (const float*)d_in[9];
    const float* ln_a_g = (const float*)d_in[10];
    const float* ln_a_b = (const float*)d_in[11];
    float* out = (float*)d_out;

    char* ws = (char*)d_ws;
    float*          Q     = (float*)(ws);                    //  65536 B
    unsigned short* W2T   = (unsigned short*)(ws + 65536);   // 262144 B
    float*          b2    = (float*)(ws + 327680);           //   2048 B
    float*          num_p = (float*)(ws + 329728);           // 33.5 MiB (512 x 64KB)
    float*          den_p = (float*)(ws + 329728 + 33554432);//  512 KiB

    hipFuncSetAttribute((const void*)k_fused,
                        hipFuncAttributeMaxDynamicSharedMemorySize, 67584);
    hipLaunchKernelGGL(k_q,    dim3(64),  dim3(256), 0, stream, mu, ln_s_g, ln_s_b, Wq, bq, Q);
    hipLaunchKernelGGL(k_fold, dim3(512), dim3(256), 0, stream, Q, Wk, bk, Wv, bv, W2T, b2);
    hipLaunchKernelGGL(k_fused, dim3(512), dim3(512), 67584, stream, X, W2T, b2, num_p, den_p);
    hipLaunchKernelGGL(k_final2, dim3(256), dim3(256), 0, stream,
                       num_p, den_p, ln_a_g, ln_a_b, out);
}